// Round 1
// baseline (61.798 us; speedup 1.0000x reference)
//
#include <hip/hip_runtime.h>
#include <math.h>

// ---- Problem constants (from reference) ----
#define KPT 9
#define NB 16
#define NH 76
#define NW 76
#define MAX_T 50
#define NCH 20                 // NA*(2K+1+NC) = 20
#define NUM_LABELS 21          // 2K+3
#define CELLS (NH*NW)          // 5776
#define IM_W 640.0f
#define IM_H 480.0f
#define DIST_THRESH 30.0f
#define SIL_THRESH 0.6f
#define OBJECT_SCALE 5.0f
#define NOOBJECT_SCALE 0.1f
#define PRETRAIN_EPOCHS 15
// c = (exp(2*(1-d/30)) - 1) / (e^2 - 1), mean over K=9
// CNORM folds the /(e^2-1)/9 normalization applied to the raw sum.
#define E2M1 5.3890560989306495f
#define CNORM (1.0f/(E2M1*9.0f))

__device__ __forceinline__ float sigmoidf_(float x) {
    return 1.0f / (1.0f + __expf(-x));
}

__global__ void zero_out_kernel(float* d_out) {
    d_out[0] = 0.0f;
}

__launch_bounds__(256)
__global__ void region_loss_kernel(const float* __restrict__ output,
                                   const float* __restrict__ target,
                                   const int* __restrict__ epoch_p,
                                   float* __restrict__ d_out)
{
    const int tid = threadIdx.x;
    const int b = blockIdx.y;

    __shared__ float s_gtx[MAX_T][KPT];   // gt x in pixels (×640)
    __shared__ float s_gty[MAX_T][KPT];   // gt y in pixels (×480)
    __shared__ float s_tx[MAX_T][KPT];    // tx_vals = gx*NW - gi0
    __shared__ float s_ty[MAX_T][KPT];    // ty_vals = gy*NH - gj0
    __shared__ float s_tconf[MAX_T];
    __shared__ int   s_cell[MAX_T];       // scatter cell or -1
    __shared__ int   s_nvalid;
    __shared__ float s_red[256];

    const float* tgb = target + (size_t)b * MAX_T * NUM_LABELS;

    // ---- validity prefix (cumprod of tgt[:,:,1] != 0) via wave-0 ballot ----
    if (tid < 64) {
        float v1 = (tid < MAX_T) ? tgb[tid * NUM_LABELS + 1] : 1.0f;
        unsigned long long zm = __ballot(v1 == 0.0f);
        if (tid == 0) {
            int fz = (zm == 0ULL) ? MAX_T : (__ffsll((long long)zm) - 1);
            s_nvalid = fz < MAX_T ? fz : MAX_T;
        }
    }

    // ---- per-target precompute into LDS (threads 0..49) ----
    if (tid < MAX_T) {
        const float* row = tgb + tid * NUM_LABELS;
        float gx0 = row[1] * (float)NW;
        float gy0 = row[2] * (float)NH;
        int gi0 = (int)gx0;               // truncation == astype(int32)
        int gj0 = (int)gy0;
        int cellt = gj0 * NW + gi0;
        int cellc = min(max(cellt, 0), CELLS - 1);
        int hc = cellc / NW, wc = cellc % NW;
        const float* ob = output + (size_t)b * NCH * CELLS + cellc;
        float csum = 0.0f;
        #pragma unroll
        for (int k = 0; k < KPT; ++k) {
            float gxk = row[1 + 2*k];
            float gyk = row[2 + 2*k];
            s_gtx[tid][k] = gxk * IM_W;
            s_gty[tid][k] = gyk * IM_H;
            s_tx[tid][k]  = gxk * (float)NW - (float)gi0;
            s_ty[tid][k]  = gyk * (float)NH - (float)gj0;
            float xo = ob[(2*k) * CELLS];
            float yo = ob[(2*k + 1) * CELLS];
            if (k == 0) { xo = sigmoidf_(xo); yo = sigmoidf_(yo); }
            float pxs = (xo + (float)wc) * (IM_W / (float)NW);
            float pys = (yo + (float)hc) * (IM_H / (float)NH);
            float dx = gxk * IM_W - pxs;
            float dy = gyk * IM_H - pys;
            float d2 = dx*dx + dy*dy;
            if (d2 < DIST_THRESH * DIST_THRESH) {
                csum += __expf(2.0f - sqrtf(d2) * (2.0f / DIST_THRESH)) - 1.0f;
            }
        }
        s_tconf[tid] = csum * CNORM;
        s_cell[tid] = (gi0 >= 0 && gi0 < NW && gj0 >= 0 && gj0 < NH) ? cellt : -1;
    }
    __syncthreads();

    const int epoch = epoch_p[0];
    const int nv = s_nvalid;
    const int cell = blockIdx.x * blockDim.x + tid;
    float contrib = 0.0f;

    if (cell < CELLS) {
        const int h = cell / NW;
        const int w = cell - h * NW;
        const float* ob = output + (size_t)b * NCH * CELLS + cell;

        float xs[KPT], ys[KPT], pxs[KPT], pys[KPT];
        #pragma unroll
        for (int k = 0; k < KPT; ++k) {
            float xo = ob[(2*k) * CELLS];
            float yo = ob[(2*k + 1) * CELLS];
            if (k == 0) { xo = sigmoidf_(xo); yo = sigmoidf_(yo); }
            xs[k] = xo; ys[k] = yo;
            pxs[k] = (xo + (float)w) * (IM_W / (float)NW);
            pys[k] = (yo + (float)h) * (IM_H / (float)NH);
        }
        const float conf = sigmoidf_(ob[2*KPT * CELLS]);

        float curmax = 0.0f;
        int winner = -1;
        for (int t = 0; t < nv; ++t) {
            float csum = 0.0f;
            #pragma unroll
            for (int k = 0; k < KPT; ++k) {
                float dx = s_gtx[t][k] - pxs[k];
                float dy = s_gty[t][k] - pys[k];
                float d2 = dx*dx + dy*dy;
                if (d2 < DIST_THRESH * DIST_THRESH) {
                    // c*(e^2-1): exp(2 - dist/15) - 1  (>=0 in-range)
                    csum += __expf(2.0f - sqrtf(d2) * (2.0f / DIST_THRESH)) - 1.0f;
                }
            }
            curmax = fmaxf(curmax, csum);
            if (s_cell[t] == cell) winner = t;   // last valid t wins (scatter .set order)
        }
        const float curconf = curmax * CNORM;

        float cmask, tconf;
        if (winner >= 0) {
            cmask = OBJECT_SCALE;
            tconf = s_tconf[winner];
            #pragma unroll
            for (int k = 0; k < KPT; ++k) {
                float dxv = xs[k] - s_tx[winner][k];
                float dyv = ys[k] - s_ty[winner][k];
                contrib += 0.5f * (dxv*dxv + dyv*dyv);   // COORD_SCALE = 1
            }
        } else {
            cmask = (curconf > SIL_THRESH) ? 0.0f : NOOBJECT_SCALE;
            tconf = 0.0f;
        }
        if (epoch > PRETRAIN_EPOCHS) {
            float d = conf - tconf;
            contrib += 0.5f * cmask * d * d;
        }
    }

    // ---- block reduction + one atomic per block ----
    s_red[tid] = contrib;
    __syncthreads();
    for (int s = 128; s > 0; s >>= 1) {
        if (tid < s) s_red[tid] += s_red[tid + s];
        __syncthreads();
    }
    if (tid == 0) atomicAdd(d_out, s_red[0]);
}

extern "C" void kernel_launch(void* const* d_in, const int* in_sizes, int n_in,
                              void* d_out, int out_size, void* d_ws, size_t ws_size,
                              hipStream_t stream) {
    const float* output = (const float*)d_in[0];
    const float* target = (const float*)d_in[1];
    const int*   epoch  = (const int*)d_in[2];
    float* out = (float*)d_out;

    zero_out_kernel<<<1, 1, 0, stream>>>(out);

    dim3 grid((CELLS + 255) / 256, NB);
    region_loss_kernel<<<grid, 256, 0, stream>>>(output, target, epoch, out);
}